// Round 3
// baseline (123.898 us; speedup 1.0000x reference)
//
#include <hip/hip_runtime.h>
#include <cmath>

#define BB 256
#define DD 768
#define LROW 260   // LDS staging row stride (floats); 1040 B, 16B-aligned

// ---------------------------------------------------------------------------
// stage1: per batch row i (256 blocks x 512 threads)
//   sim[t][s] = ls*<vl[i,t,:], tl[i,s,:]>; tw = softmax_t(max_s sim)
//   vw[i,:] = sum_t tw[t]*vl[i,t,:];  tb[i,:] = mean_s tl[i,s,:]
// K partitioned: slice = tid&15 owns d = slice*4 + {0,64,128,192} per chunk.
//   db = step*64 + slice*4 => within-row contiguous LDS reads (A-frag ~2cy
//   broadcast, B-frag at the 1KB/instr b128 floor — no 8-way conflicts).
// Register double-buffer: prefetch chunk c+1 during compute of chunk c.
// Block 0 also zeroes out[0] (replaces the memset dispatch).
// ---------------------------------------------------------------------------
__global__ __launch_bounds__(512) void hl_stage1(
    const float* __restrict__ vl, const float* __restrict__ tl,
    const float* __restrict__ temp,
    float* __restrict__ vw_ws, float* __restrict__ tb_ws,
    float* __restrict__ out)
{
    __shared__ float smem[12480];   // 48 x 260 staging; aliased as 512x17 transpose
    __shared__ float simb[512];
    __shared__ float rmax[16];
    __shared__ float twb[16];

    const int i   = blockIdx.x;
    const int tid = threadIdx.x;
    if (i == 0 && tid == 0) out[0] = 0.f;   // lse (later dispatch) accumulates
    const float lsc = expf(temp[0]);

    const int slice = tid & 15;
    const int g     = tid >> 4;   // 0..31
    const int tg    = g >> 3;     // 0..3
    const int sg    = g & 7;      // 0..7

    const float* vli = vl + (size_t)i * 16 * DD;
    const float* tli = tl + (size_t)i * 32 * DD;

    // prefetch chunk 0 into registers
    float4 va[2], ta[4];
#pragma unroll
    for (int k = 0; k < 2; ++k) {
        int f4 = tid + (k << 9);
        va[k] = *(const float4*)&vli[(f4 >> 6) * DD + ((f4 & 63) << 2)];
    }
#pragma unroll
    for (int k = 0; k < 4; ++k) {
        int f4 = tid + (k << 9);
        ta[k] = *(const float4*)&tli[(f4 >> 6) * DD + ((f4 & 63) << 2)];
    }

    float acc[4][4];
#pragma unroll
    for (int a = 0; a < 4; ++a)
#pragma unroll
        for (int b = 0; b < 4; ++b) acc[a][b] = 0.f;

    for (int c = 0; c < 3; ++c) {
        // write staged regs -> LDS (prev readers done: trailing barrier)
#pragma unroll
        for (int k = 0; k < 2; ++k) {
            int f4 = tid + (k << 9);
            *(float4*)&smem[(f4 >> 6) * LROW + ((f4 & 63) << 2)] = va[k];
        }
#pragma unroll
        for (int k = 0; k < 4; ++k) {
            int f4 = tid + (k << 9);
            *(float4*)&smem[(16 + (f4 >> 6)) * LROW + ((f4 & 63) << 2)] = ta[k];
        }
        __syncthreads();
        // prefetch next chunk (waitcnt deferred to next iteration's LDS write)
        if (c < 2) {
            const int d0 = (c + 1) << 8;
#pragma unroll
            for (int k = 0; k < 2; ++k) {
                int f4 = tid + (k << 9);
                va[k] = *(const float4*)&vli[(f4 >> 6) * DD + d0 + ((f4 & 63) << 2)];
            }
#pragma unroll
            for (int k = 0; k < 4; ++k) {
                int f4 = tid + (k << 9);
                ta[k] = *(const float4*)&tli[(f4 >> 6) * DD + d0 + ((f4 & 63) << 2)];
            }
        }
        // compute on chunk c
#pragma unroll
        for (int step = 0; step < 4; ++step) {
            const int db = (step << 6) + (slice << 2);
            float4 av[4], bv[4];
#pragma unroll
            for (int ti = 0; ti < 4; ++ti)
                av[ti] = *(const float4*)&smem[(tg * 4 + ti) * LROW + db];
#pragma unroll
            for (int sj = 0; sj < 4; ++sj)
                bv[sj] = *(const float4*)&smem[(16 + sg * 4 + sj) * LROW + db];
#pragma unroll
            for (int ti = 0; ti < 4; ++ti)
#pragma unroll
                for (int sj = 0; sj < 4; ++sj)
                    acc[ti][sj] += av[ti].x * bv[sj].x + av[ti].y * bv[sj].y
                                 + av[ti].z * bv[sj].z + av[ti].w * bv[sj].w;
        }
        // tb for this chunk's 256 d-columns, straight from LDS
        if (tid < 256) {
            float s2 = 0.f;
#pragma unroll
            for (int s = 0; s < 32; ++s) s2 += smem[(16 + s) * LROW + tid];
            tb_ws[(size_t)i * DD + (c << 8) + tid] = s2 * (1.0f / 32.0f);
        }
        __syncthreads();   // all smem reads done before next overwrite
    }

    // split-D transpose (alias staging region): [pair][slice], pad 17
#pragma unroll
    for (int ti = 0; ti < 4; ++ti)
#pragma unroll
        for (int sj = 0; sj < 4; ++sj) {
            int t = tg * 4 + ti, s = sg * 4 + sj;
            smem[(t * 32 + s) * 17 + slice] = acc[ti][sj];
        }
    __syncthreads();
    {   // pair `tid` reduce over 16 slices
        float ssum = 0.f;
#pragma unroll
        for (int k = 0; k < 16; ++k) ssum += smem[tid * 17 + k];
        simb[tid] = lsc * ssum;
    }
    __syncthreads();
    if (tid < 16) {               // rowmax over s (rotated to avoid bank clash)
        float m = -3.0e38f;
        for (int s = 0; s < 32; ++s)
            m = fmaxf(m, simb[tid * 32 + ((s + tid) & 31)]);
        rmax[tid] = m;
    }
    __syncthreads();
    if (tid == 0) {               // tw = softmax over 16 t values
        float M = -3.0e38f;
        for (int t = 0; t < 16; ++t) M = fmaxf(M, rmax[t]);
        float ssum = 0.f;
        for (int t = 0; t < 16; ++t) {
            float e = expf(rmax[t] - M);
            twb[t] = e;
            ssum += e;
        }
        float inv = 1.0f / ssum;
        for (int t = 0; t < 16; ++t) twb[t] *= inv;
    }
    __syncthreads();

    // vw tail: coalesced, vl rows L2-hot
    for (int d = tid; d < DD; d += 512) {
        float vwv = 0.f;
#pragma unroll
        for (int t = 0; t < 16; ++t) vwv += twb[t] * vli[t * DD + d];
        vw_ws[(size_t)i * DD + d] = vwv;
    }
}

// ---------------------------------------------------------------------------
// hl_gemm: 256 blocks = mat(2) x ti(4) x tj(4) x p(8 K-splits of 96)
//   mat 0: G = ls*vg@tg^T  -> cparts[p][1] and transposed into cparts[p][2]
//   mat 1: L = ls*vw@tb^T  -> cparts[p][0]
// ---------------------------------------------------------------------------
__global__ __launch_bounds__(256) void hl_gemm(
    const float* __restrict__ vg, const float* __restrict__ tg,
    const float* __restrict__ vw, const float* __restrict__ tb,
    const float* __restrict__ temp, float* __restrict__ cparts)
{
    __shared__ float As[16][68];
    __shared__ float Bs[16][68];
    __shared__ float Tb[64][68];

    const int b   = blockIdx.x;
    const int p   = b & 7;
    const int tj  = (b >> 3) & 3;
    const int ti  = (b >> 5) & 3;
    const int mat = b >> 7;
    const int tid = threadIdx.x;
    const float lsc = expf(temp[0]);

    const float* A  = mat ? vw : vg;
    const float* Bm = mat ? tb : tg;
    const int i0 = ti * 64, j0 = tj * 64, kb0 = p * 96;

    const int srow = tid >> 2, skq = tid & 3;
    const int tr = tid >> 4, tc = tid & 15;

    float acc[4][4];
#pragma unroll
    for (int r = 0; r < 4; ++r)
#pragma unroll
        for (int cc = 0; cc < 4; ++cc) acc[r][cc] = 0.f;

    for (int ch = 0; ch < 6; ++ch) {
        const int kb = kb0 + ch * 16;
        float4 a4 = *(const float4*)&A [(size_t)(i0 + srow) * DD + kb + skq * 4];
        float4 b4 = *(const float4*)&Bm[(size_t)(j0 + srow) * DD + kb + skq * 4];
        __syncthreads();
        As[skq * 4 + 0][srow] = a4.x; As[skq * 4 + 1][srow] = a4.y;
        As[skq * 4 + 2][srow] = a4.z; As[skq * 4 + 3][srow] = a4.w;
        Bs[skq * 4 + 0][srow] = b4.x; Bs[skq * 4 + 1][srow] = b4.y;
        Bs[skq * 4 + 2][srow] = b4.z; Bs[skq * 4 + 3][srow] = b4.w;
        __syncthreads();
#pragma unroll
        for (int k = 0; k < 16; ++k) {
            float4 av = *(const float4*)&As[k][tr * 4];
            float4 bv = *(const float4*)&Bs[k][tc * 4];
            float ar[4] = {av.x, av.y, av.z, av.w};
            float br[4] = {bv.x, bv.y, bv.z, bv.w};
#pragma unroll
            for (int r = 0; r < 4; ++r)
#pragma unroll
                for (int cc = 0; cc < 4; ++cc)
                    acc[r][cc] += ar[r] * br[cc];
        }
    }

    const int cm = mat ? 0 : 1;
    float* Cp = cparts + ((size_t)p * 3 + cm) * 65536;
#pragma unroll
    for (int r = 0; r < 4; ++r) {
        float4 v = {acc[r][0] * lsc, acc[r][1] * lsc, acc[r][2] * lsc, acc[r][3] * lsc};
        *(float4*)&Cp[(size_t)(i0 + tr * 4 + r) * 256 + j0 + tc * 4] = v;
    }
    if (mat == 0) {   // also write G^T for the t2v column-LSE
        __syncthreads();
#pragma unroll
        for (int r = 0; r < 4; ++r)
#pragma unroll
            for (int cc = 0; cc < 4; ++cc)
                Tb[tc * 4 + cc][tr * 4 + r] = acc[r][cc] * lsc;
        __syncthreads();
        float* Ct = cparts + ((size_t)p * 3 + 2) * 65536;
#pragma unroll
        for (int r = 0; r < 4; ++r) {
            float4 v = *(const float4*)&Tb[tr * 4 + r][tc * 4];
            *(float4*)&Ct[(size_t)(j0 + tr * 4 + r) * 256 + i0 + tc * 4] = v;
        }
    }
}

// ---------------------------------------------------------------------------
// hl_lse: 768 blocks = cm(3) x row(256). Sum 8 K-partials, block LSE,
// weighted atomicAdd of (lse - x[row]) into out.
// ---------------------------------------------------------------------------
__global__ __launch_bounds__(256) void hl_lse(
    const float* __restrict__ cparts, float* __restrict__ out)
{
    __shared__ float xs[256];
    __shared__ float wred[4];
    __shared__ float bcast;

    const int b   = blockIdx.x;
    const int cm  = b >> 8;
    const int row = b & 255;
    const int tid = threadIdx.x;

    float x = 0.f;
#pragma unroll
    for (int p = 0; p < 8; ++p)
        x += cparts[((size_t)p * 3 + cm) * 65536 + (size_t)row * 256 + tid];
    xs[tid] = x;

    float m = x;
#pragma unroll
    for (int off = 32; off > 0; off >>= 1)
        m = fmaxf(m, __shfl_down(m, off, 64));
    if ((tid & 63) == 0) wred[tid >> 6] = m;
    __syncthreads();
    if (tid == 0)
        bcast = fmaxf(fmaxf(wred[0], wred[1]), fmaxf(wred[2], wred[3]));
    __syncthreads();
    float M = bcast;
    float e = expf(x - M);
#pragma unroll
    for (int off = 32; off > 0; off >>= 1)
        e += __shfl_down(e, off, 64);
    if ((tid & 63) == 0) wred[tid >> 6] = e;
    __syncthreads();
    if (tid == 0) {
        float Stot = wred[0] + wred[1] + wred[2] + wred[3];
        float lse  = M + logf(Stot);
        float w    = (cm == 0) ? (0.4f / 256.0f) : (0.3f / 256.0f);
        atomicAdd(out, w * (lse - xs[row]));
    }
}

extern "C" void kernel_launch(void* const* d_in, const int* in_sizes, int n_in,
                              void* d_out, int out_size, void* d_ws, size_t ws_size,
                              hipStream_t stream)
{
    const float* vg   = (const float*)d_in[0];  // [256,768]
    const float* tg   = (const float*)d_in[1];  // [256,768]
    const float* vl   = (const float*)d_in[2];  // [256,16,768]
    const float* tl   = (const float*)d_in[3];  // [256,32,768]
    const float* temp = (const float*)d_in[4];  // [1]
    float* out = (float*)d_out;

    float* vw     = (float*)d_ws;                   // [256,768]
    float* tb     = vw + (size_t)BB * DD;           // [256,768]
    float* cparts = tb + (size_t)BB * DD;           // [8][3][256][256]

    hl_stage1<<<dim3(BB),  dim3(512), 0, stream>>>(vl, tl, temp, vw, tb, out);
    hl_gemm  <<<dim3(256), dim3(256), 0, stream>>>(vg, tg, vw, tb, temp, cparts);
    hl_lse   <<<dim3(768), dim3(256), 0, stream>>>(cparts, out);
}